// Round 1
// baseline (736.138 us; speedup 1.0000x reference)
//
#include <hip/hip_runtime.h>

#define EPS 1e-5f

constexpr int NTc = 32;   // B*T
constexpr int CLc = 96;
constexpr int HSc = 64;
constexpr int WSc = 64;
constexpr int DIMc = 64;
constexpr int Gc = 8;

// per-b attention. dst is either ws laid out (b, d, cl) [DIRECT=false]
// or the final output laid out (nt, cl, d, hs) [DIRECT=true].
template<bool DIRECT>
__global__ __launch_bounds__(256) void attn_kernel(
    const float* __restrict__ x,
    const float* __restrict__ w,
    const float* __restrict__ qkv_gamma, const float* __restrict__ qkv_beta,
    const float* __restrict__ qkv_mean,  const float* __restrict__ qkv_var,
    const float* __restrict__ sim_gamma, const float* __restrict__ sim_beta,
    const float* __restrict__ sim_mean,  const float* __restrict__ sim_var,
    const float* __restrict__ out_gamma, const float* __restrict__ out_beta,
    const float* __restrict__ out_mean,  const float* __restrict__ out_var,
    float* __restrict__ dst)
{
    // LDS budget: 24960 + 4096 + 6208 + 18624 + 768 + 192 = 54848 B (< 64 KB)
    __shared__ float Xs[CLc][WSc + 1];    // [cl][ws], pad -> stride 65 (conflict-free when lanes vary cl)
    __shared__ float Wg[16][WSc];         // current group's 16 w rows
    __shared__ float QKVg[16][CLc + 1];   // BN'd q(0..3) k(4..7) v(8..15)
    __shared__ float QK[48][CLc + 1];     // score tile (48 rows of i), pad 97
    __shared__ float part[48][4];
    __shared__ float rowZinv[48];

    const int tid = threadIdx.x;
    const int b  = blockIdx.x;          // b = nt*64 + hs
    const int nt = b >> 6;
    const int hs = b & 63;

    // x[nt, cl, hs, ws] : slice for this b = base + cl*4096 + ws (ws contiguous)
    const float* xb = x + (size_t)nt * 393216 + (size_t)hs * 64;
    const float4* x4 = reinterpret_cast<const float4*>(xb);

    for (int idx = tid; idx < CLc * 16; idx += 256) {
        int cl = idx >> 4, wv = idx & 15;
        float4 v = x4[cl * 1024 + wv];          // (cl*4096 + wv*4)/4
        int ws = wv * 4;
        Xs[cl][ws + 0] = v.x; Xs[cl][ws + 1] = v.y;
        Xs[cl][ws + 2] = v.z; Xs[cl][ws + 3] = v.w;
    }
    __syncthreads();

    for (int g = 0; g < Gc; ++g) {
        // stage this group's 16 weight rows (o = g*16 + r)
        for (int idx = tid; idx < 16 * 64; idx += 256) {
            int r = idx >> 6, kk = idx & 63;
            Wg[r][kk] = w[(size_t)((g << 4) + r) * 64 + kk];
        }
        __syncthreads();

        // qkv[r][l] = BN( sum_ws Wg[r][ws] * Xs[l][ws] )
        for (int idx = tid; idx < 16 * CLc; idx += 256) {
            int r = idx / CLc, l = idx - r * CLc;
            float acc = 0.f;
            #pragma unroll
            for (int kk = 0; kk < WSc; ++kk) acc += Wg[r][kk] * Xs[l][kk];
            int o = (g << 4) + r;
            float sc = qkv_gamma[o] * rsqrtf(qkv_var[o] + EPS);
            QKVg[r][l] = (acc - qkv_mean[o]) * sc + qkv_beta[o];
        }
        __syncthreads();

        const float simA = sim_gamma[g] * rsqrtf(sim_var[g] + EPS);
        const float simB = sim_beta[g] - sim_mean[g] * simA;

        for (int it = 0; it < 2; ++it) {
            // scores: QK[ii][j] = BN( sum_c q[c][i]*k[c][j] ),  i = it*48+ii
            for (int idx = tid; idx < 48 * CLc; idx += 256) {
                int ii = idx / CLc, j = idx - ii * CLc;
                int i = it * 48 + ii;
                float acc = 0.f;
                #pragma unroll
                for (int c = 0; c < 4; ++c) acc += QKVg[c][i] * QKVg[4 + c][j];
                QK[ii][j] = acc * simA + simB;
            }
            __syncthreads();

            // exp + row partial sums (values bounded ~|15| -> no max-subtraction needed in fp32)
            if (tid < 192) {
                int r = tid >> 2, q = tid & 3;
                float s = 0.f;
                #pragma unroll
                for (int j = 0; j < 24; ++j) {
                    float e = __expf(QK[r][q * 24 + j]);
                    QK[r][q * 24 + j] = e;
                    s += e;
                }
                part[r][q] = s;
            }
            __syncthreads();
            if (tid < 48) {
                rowZinv[tid] = 1.f / (part[tid][0] + part[tid][1] + part[tid][2] + part[tid][3]);
            }
            __syncthreads();

            // sv[c][i] = (sum_j exp[i][j] * v[c][j]) / Z_i, then out-BN, write
            for (int idx = tid; idx < 8 * 48; idx += 256) {
                int c = idx / 48, ii = idx - c * 48;
                float acc = 0.f;
                #pragma unroll
                for (int j = 0; j < CLc; ++j) acc += QK[ii][j] * QKVg[8 + c][j];
                acc *= rowZinv[ii];
                int d = (g << 3) + c;
                float sc = out_gamma[d] * rsqrtf(out_var[d] + EPS);
                float val = (acc - out_mean[d]) * sc + out_beta[d];
                int i = it * 48 + ii;
                if (DIRECT) {
                    // out[nt, cl=i, d, hs]
                    dst[(size_t)nt * 393216 + (size_t)i * 4096 + (size_t)d * 64 + hs] = val;
                } else {
                    // ws[b, d, cl=i]
                    dst[(size_t)b * 6144 + (size_t)d * 96 + i] = val;
                }
            }
            __syncthreads();  // protect QK/QKVg reuse
        }
    }
}

// ws (nt, hs, d, cl) -> out (nt, cl, d, hs): for fixed (nt,d) a 64(hs) x 96(cl) transpose
__global__ __launch_bounds__(256) void transpose_kernel(const float* __restrict__ ws,
                                                        float* __restrict__ out)
{
    __shared__ float tile[64][97];
    const int blk = blockIdx.x;          // nt*64 + d
    const int nt = blk >> 6, d = blk & 63;

    const float* src = ws + (size_t)nt * 64 * 6144 + (size_t)d * 96;
    for (int idx = threadIdx.x; idx < 6144; idx += 256) {
        int hs = idx / 96, cl = idx - hs * 96;
        tile[hs][cl] = src[(size_t)hs * 6144 + cl];   // 96-float contiguous rows
    }
    __syncthreads();

    float* dstp = out + (size_t)nt * 393216 + (size_t)d * 64;
    for (int idx = threadIdx.x; idx < 6144; idx += 256) {
        int cl = idx >> 6, hs = idx & 63;
        dstp[(size_t)cl * 4096 + hs] = tile[hs][cl];  // 64-float contiguous rows
    }
}

extern "C" void kernel_launch(void* const* d_in, const int* in_sizes, int n_in,
                              void* d_out, int out_size, void* d_ws, size_t ws_size,
                              hipStream_t stream) {
    const float* x         = (const float*)d_in[0];
    const float* w_qkv     = (const float*)d_in[1];
    const float* qkv_gamma = (const float*)d_in[2];
    const float* qkv_beta  = (const float*)d_in[3];
    const float* qkv_mean  = (const float*)d_in[4];
    const float* qkv_var   = (const float*)d_in[5];
    const float* sim_gamma = (const float*)d_in[6];
    const float* sim_beta  = (const float*)d_in[7];
    const float* sim_mean  = (const float*)d_in[8];
    const float* sim_var   = (const float*)d_in[9];
    const float* out_gamma = (const float*)d_in[10];
    const float* out_beta  = (const float*)d_in[11];
    const float* out_mean  = (const float*)d_in[12];
    const float* out_var   = (const float*)d_in[13];
    float* out = (float*)d_out;

    const size_t ws_need = (size_t)2048 * 6144 * sizeof(float);  // 50.3 MB

    if (ws_size >= ws_need) {
        float* wsb = (float*)d_ws;
        attn_kernel<false><<<2048, 256, 0, stream>>>(
            x, w_qkv, qkv_gamma, qkv_beta, qkv_mean, qkv_var,
            sim_gamma, sim_beta, sim_mean, sim_var,
            out_gamma, out_beta, out_mean, out_var, wsb);
        transpose_kernel<<<2048, 256, 0, stream>>>(wsb, out);
    } else {
        attn_kernel<true><<<2048, 256, 0, stream>>>(
            x, w_qkv, qkv_gamma, qkv_beta, qkv_mean, qkv_var,
            sim_gamma, sim_beta, sim_mean, sim_var,
            out_gamma, out_beta, out_mean, out_var, out);
    }
}

// Round 2
// 334.024 us; speedup vs baseline: 2.2038x; 2.2038x over previous
//
#include <hip/hip_runtime.h>

#define EPS 1e-5f

constexpr int Gc = 8;

// Per-b fused attention.
// Phase 1: QKV[128][96] = BN(W(128x64) @ X(64x96)) for ALL groups, register-tiled 4x12,
//          W streamed from global (L1-resident, shared by all blocks), X staged in LDS half-K.
// Phase 2: per group: scores(96x96,K=4) -> exp -> rowsum(shfl) -> PV(8x96,K=96) -> 8-way
//          j-split reduction via shfl -> BN -> staged coalesced store.
template<bool DIRECT>
__global__ __launch_bounds__(256) void attn_kernel(
    const float* __restrict__ x,
    const float* __restrict__ w,
    const float* __restrict__ qkv_gamma, const float* __restrict__ qkv_beta,
    const float* __restrict__ qkv_mean,  const float* __restrict__ qkv_var,
    const float* __restrict__ sim_gamma, const float* __restrict__ sim_beta,
    const float* __restrict__ sim_mean,  const float* __restrict__ sim_var,
    const float* __restrict__ out_gamma, const float* __restrict__ out_beta,
    const float* __restrict__ out_mean,  const float* __restrict__ out_var,
    float* __restrict__ dst)
{
    // 128*97*4 = 49664 B + 96*34*4 = 13056 B  -> 62720 B total LDS
    __shared__ float QKV[128][97];
    __shared__ __align__(16) float shreg[96 * 34];   // phase1: Xs[96][34]; phase2: 768-float store staging

    const int tid = threadIdx.x;
    const int b  = blockIdx.x;          // b = nt*64 + hs
    const int nt = b >> 6;
    const int hs = b & 63;

    const float* xb = x + (size_t)nt * 393216 + (size_t)hs * 64;
    const float4* x4 = reinterpret_cast<const float4*>(xb);
    const float2* w2 = reinterpret_cast<const float2*>(w);

    // ---------------- Phase 1: QKV = BN(W @ X) ----------------
    const int trb = tid >> 3;   // 0..31 : rows r = trb*4 + rr
    const int tcb = tid & 7;    // 0..7  : cols l = tcb*12 + jj

    float acc[4][12];
    #pragma unroll
    for (int rr = 0; rr < 4; ++rr)
        #pragma unroll
        for (int jj = 0; jj < 12; ++jj) acc[rr][jj] = 0.f;

    float (*Xs)[34] = reinterpret_cast<float(*)[34]>(shreg);

    for (int pass = 0; pass < 2; ++pass) {
        // stage 96 x 32 floats (half of K)
        for (int idx = tid; idx < 768; idx += 256) {
            int cl = idx >> 3, v = idx & 7;
            float4 val = x4[cl * 1024 + pass * 8 + v];
            float2* dx = reinterpret_cast<float2*>(&Xs[cl][v * 4]);
            dx[0] = make_float2(val.x, val.y);
            dx[1] = make_float2(val.z, val.w);
        }
        __syncthreads();

        for (int kh = 0; kh < 16; ++kh) {
            float2 wr[4], xr[12];
            #pragma unroll
            for (int rr = 0; rr < 4; ++rr)
                wr[rr] = w2[(trb * 4 + rr) * 32 + pass * 16 + kh];
            #pragma unroll
            for (int jj = 0; jj < 12; ++jj)
                xr[jj] = *reinterpret_cast<const float2*>(&Xs[tcb * 12 + jj][kh * 2]);
            #pragma unroll
            for (int rr = 0; rr < 4; ++rr)
                #pragma unroll
                for (int jj = 0; jj < 12; ++jj)
                    acc[rr][jj] += wr[rr].x * xr[jj].x + wr[rr].y * xr[jj].y;
        }
        __syncthreads();   // protect Xs before reload / reuse as staging buffer
    }

    // BN + write QKV
    #pragma unroll
    for (int rr = 0; rr < 4; ++rr) {
        int o = trb * 4 + rr;
        float sc = qkv_gamma[o] * rsqrtf(qkv_var[o] + EPS);
        float mb = qkv_beta[o] - qkv_mean[o] * sc;
        #pragma unroll
        for (int jj = 0; jj < 12; ++jj)
            QKV[o][tcb * 12 + jj] = acc[rr][jj] * sc + mb;
    }
    __syncthreads();

    // ---------------- Phase 2: per-group attention ----------------
    const int ib = tid >> 3;    // 0..31 : rows i = ib*3 + ii
    const int jb = tid & 7;     // 0..7  : cols j = jb*12 + jj
    float* finalbuf = shreg;    // 768 floats

    for (int g = 0; g < Gc; ++g) {
        const int gb = g * 16;
        const float simA = sim_gamma[g] * rsqrtf(sim_var[g] + EPS);
        // (sim_beta and -mean*simA are j-independent -> cancel in softmax)

        float q[4][3];
        #pragma unroll
        for (int c = 0; c < 4; ++c)
            #pragma unroll
            for (int ii = 0; ii < 3; ++ii)
                q[c][ii] = QKV[gb + c][ib * 3 + ii];

        float sim[3][12];
        #pragma unroll
        for (int ii = 0; ii < 3; ++ii)
            #pragma unroll
            for (int jj = 0; jj < 12; ++jj) sim[ii][jj] = 0.f;

        #pragma unroll
        for (int c = 0; c < 4; ++c)
            #pragma unroll
            for (int jj = 0; jj < 12; ++jj) {
                float kv = QKV[gb + 4 + c][jb * 12 + jj];
                #pragma unroll
                for (int ii = 0; ii < 3; ++ii)
                    sim[ii][jj] += q[c][ii] * kv;
            }

        float p[3] = {0.f, 0.f, 0.f};
        #pragma unroll
        for (int ii = 0; ii < 3; ++ii)
            #pragma unroll
            for (int jj = 0; jj < 12; ++jj) {
                float e = __expf(simA * sim[ii][jj]);
                sim[ii][jj] = e;
                p[ii] += e;
            }
        // row sum across the 8 jb lanes (jb = lane&7 -> in-wave butterfly)
        #pragma unroll
        for (int ii = 0; ii < 3; ++ii) {
            p[ii] += __shfl_xor(p[ii], 1);
            p[ii] += __shfl_xor(p[ii], 2);
            p[ii] += __shfl_xor(p[ii], 4);
        }
        float zinv[3] = {1.f / p[0], 1.f / p[1], 1.f / p[2]};

        float sv[8][3];
        #pragma unroll
        for (int c = 0; c < 8; ++c)
            #pragma unroll
            for (int ii = 0; ii < 3; ++ii) sv[c][ii] = 0.f;

        #pragma unroll
        for (int jj = 0; jj < 12; ++jj) {
            #pragma unroll
            for (int c = 0; c < 8; ++c) {
                float v = QKV[gb + 8 + c][jb * 12 + jj];
                #pragma unroll
                for (int ii = 0; ii < 3; ++ii)
                    sv[c][ii] += sim[ii][jj] * v;
            }
        }
        // reduce partial sv across jb lanes
        #pragma unroll
        for (int c = 0; c < 8; ++c)
            #pragma unroll
            for (int ii = 0; ii < 3; ++ii) {
                sv[c][ii] += __shfl_xor(sv[c][ii], 1);
                sv[c][ii] += __shfl_xor(sv[c][ii], 2);
                sv[c][ii] += __shfl_xor(sv[c][ii], 4);
            }

        if (jb == 0) {
            #pragma unroll
            for (int c = 0; c < 8; ++c) {
                int d = g * 8 + c;
                float osc = out_gamma[d] * rsqrtf(out_var[d] + EPS);
                float ob  = out_beta[d] - out_mean[d] * osc;
                #pragma unroll
                for (int ii = 0; ii < 3; ++ii)
                    finalbuf[c * 96 + ib * 3 + ii] = sv[c][ii] * zinv[ii] * osc + ob;
            }
        }
        __syncthreads();

        if (DIRECT) {
            #pragma unroll
            for (int t = 0; t < 3; ++t) {
                int idx = tid * 3 + t;
                int d = idx / 96, cl = idx - d * 96;
                dst[(size_t)nt * 393216 + (size_t)cl * 4096 + (size_t)(g * 8 + d) * 64 + hs]
                    = finalbuf[idx];
            }
        } else {
            if (tid < 192) {
                float4 vv = reinterpret_cast<const float4*>(finalbuf)[tid];
                reinterpret_cast<float4*>(dst + (size_t)b * 6144 + g * 768)[tid] = vv;
            }
        }
        __syncthreads();   // finalbuf reused next group
    }
}

// ws (nt, hs, d, cl) -> out (nt, cl, d, hs): for fixed (nt,d) a 64(hs) x 96(cl) transpose
__global__ __launch_bounds__(256) void transpose_kernel(const float* __restrict__ ws,
                                                        float* __restrict__ out)
{
    __shared__ float tile[64][97];
    const int blk = blockIdx.x;          // nt*64 + d
    const int nt = blk >> 6, d = blk & 63;
    const float4* ws4 = reinterpret_cast<const float4*>(ws);
    float4* out4 = reinterpret_cast<float4*>(out);

    for (int idx = threadIdx.x; idx < 1536; idx += 256) {
        int hs = idx / 24, c4 = idx - hs * 24;
        float4 v = ws4[(size_t)nt * 98304 + (size_t)hs * 1536 + d * 24 + c4];
        tile[hs][c4 * 4 + 0] = v.x; tile[hs][c4 * 4 + 1] = v.y;
        tile[hs][c4 * 4 + 2] = v.z; tile[hs][c4 * 4 + 3] = v.w;
    }
    __syncthreads();

    for (int idx = threadIdx.x; idx < 1536; idx += 256) {
        int cl = idx >> 4, h4 = idx & 15;
        float4 v = make_float4(tile[h4 * 4 + 0][cl], tile[h4 * 4 + 1][cl],
                               tile[h4 * 4 + 2][cl], tile[h4 * 4 + 3][cl]);
        out4[(size_t)nt * 98304 + (size_t)cl * 1024 + d * 16 + h4] = v;
    }
}

extern "C" void kernel_launch(void* const* d_in, const int* in_sizes, int n_in,
                              void* d_out, int out_size, void* d_ws, size_t ws_size,
                              hipStream_t stream) {
    const float* x         = (const float*)d_in[0];
    const float* w_qkv     = (const float*)d_in[1];
    const float* qkv_gamma = (const float*)d_in[2];
    const float* qkv_beta  = (const float*)d_in[3];
    const float* qkv_mean  = (const float*)d_in[4];
    const float* qkv_var   = (const float*)d_in[5];
    const float* sim_gamma = (const float*)d_in[6];
    const float* sim_beta  = (const float*)d_in[7];
    const float* sim_mean  = (const float*)d_in[8];
    const float* sim_var   = (const float*)d_in[9];
    const float* out_gamma = (const float*)d_in[10];
    const float* out_beta  = (const float*)d_in[11];
    const float* out_mean  = (const float*)d_in[12];
    const float* out_var   = (const float*)d_in[13];
    float* out = (float*)d_out;

    const size_t ws_need = (size_t)2048 * 6144 * sizeof(float);  // 50.3 MB

    if (ws_size >= ws_need) {
        float* wsb = (float*)d_ws;
        attn_kernel<false><<<2048, 256, 0, stream>>>(
            x, w_qkv, qkv_gamma, qkv_beta, qkv_mean, qkv_var,
            sim_gamma, sim_beta, sim_mean, sim_var,
            out_gamma, out_beta, out_mean, out_var, wsb);
        transpose_kernel<<<2048, 256, 0, stream>>>(wsb, out);
    } else {
        attn_kernel<true><<<2048, 256, 0, stream>>>(
            x, w_qkv, qkv_gamma, qkv_beta, qkv_mean, qkv_var,
            sim_gamma, sim_beta, sim_mean, sim_var,
            out_gamma, out_beta, out_mean, out_var, out);
    }
}

// Round 3
// 299.490 us; speedup vs baseline: 2.4580x; 1.1153x over previous
//
#include <hip/hip_runtime.h>

#define EPS 1e-5f

// Per-b fused attention, 3 blocks/CU.
// LDS: one 53,248 B region, time-multiplexed:
//   phase 1a: Xs[96][66]  (X staged full-K)        -- dead after compute
//   phase 1b+2: QKV[128][104]; cols 96..103 = 1024-float pad used as store staging.
template<bool DIRECT>
__global__ __launch_bounds__(256, 3) void attn_kernel(
    const float* __restrict__ x,
    const float* __restrict__ w,
    const float* __restrict__ qkv_gamma, const float* __restrict__ qkv_beta,
    const float* __restrict__ qkv_mean,  const float* __restrict__ qkv_var,
    const float* __restrict__ sim_gamma, const float* __restrict__ sim_beta,
    const float* __restrict__ sim_mean,  const float* __restrict__ sim_var,
    const float* __restrict__ out_gamma, const float* __restrict__ out_beta,
    const float* __restrict__ out_mean,  const float* __restrict__ out_var,
    float* __restrict__ dst)
{
    __shared__ __align__(16) float smraw[128 * 104];   // 53,248 B
    float (*QKV)[104] = reinterpret_cast<float(*)[104]>(smraw);
    float (*Xs)[66]   = reinterpret_cast<float(*)[66]>(smraw);   // 25,344 B overlay

    const int tid = threadIdx.x;
    const int b  = blockIdx.x;          // b = nt*64 + hs
    const int nt = b >> 6;
    const int hs = b & 63;

    const float* xb = x + (size_t)nt * 393216 + (size_t)hs * 64;
    const float4* x4 = reinterpret_cast<const float4*>(xb);
    const float4* w4 = reinterpret_cast<const float4*>(w);

    // ---------------- Phase 1: QKV = BN(W @ X), full-K staging ----------------
    const int trb = tid >> 3;   // 0..31 : rows r = trb*4 + rr
    const int tcb = tid & 7;    // 0..7  : cols l = tcb*12 + jj

    for (int idx = tid; idx < 1536; idx += 256) {
        int cl = idx >> 4, v = idx & 15;
        float4 val = x4[cl * 1024 + v];              // 256B-aligned contiguous rows
        float2* dx = reinterpret_cast<float2*>(&Xs[cl][v * 4]);
        dx[0] = make_float2(val.x, val.y);
        dx[1] = make_float2(val.z, val.w);
    }
    __syncthreads();

    float acc[4][12];
    #pragma unroll
    for (int rr = 0; rr < 4; ++rr)
        #pragma unroll
        for (int jj = 0; jj < 12; ++jj) acc[rr][jj] = 0.f;

    #pragma unroll 4
    for (int kh = 0; kh < 16; ++kh) {               // 4 k per iter
        float4 wr[4];
        #pragma unroll
        for (int rr = 0; rr < 4; ++rr)
            wr[rr] = w4[(trb * 4 + rr) * 16 + kh];
        #pragma unroll
        for (int jj = 0; jj < 12; ++jj) {
            float2 xa = *reinterpret_cast<const float2*>(&Xs[tcb * 12 + jj][kh * 4]);
            float2 xc = *reinterpret_cast<const float2*>(&Xs[tcb * 12 + jj][kh * 4 + 2]);
            #pragma unroll
            for (int rr = 0; rr < 4; ++rr)
                acc[rr][jj] += wr[rr].x * xa.x + wr[rr].y * xa.y
                             + wr[rr].z * xc.x + wr[rr].w * xc.y;
        }
    }
    __syncthreads();    // Xs dead; safe to overwrite region with QKV

    #pragma unroll
    for (int rr = 0; rr < 4; ++rr) {
        int o = trb * 4 + rr;
        float sc = qkv_gamma[o] * rsqrtf(qkv_var[o] + EPS);
        float mb = qkv_beta[o] - qkv_mean[o] * sc;
        #pragma unroll
        for (int m = 0; m < 3; ++m) {
            float4 vv;
            vv.x = acc[rr][m * 4 + 0] * sc + mb;
            vv.y = acc[rr][m * 4 + 1] * sc + mb;
            vv.z = acc[rr][m * 4 + 2] * sc + mb;
            vv.w = acc[rr][m * 4 + 3] * sc + mb;
            *reinterpret_cast<float4*>(&QKV[o][tcb * 12 + m * 4]) = vv;
        }
    }
    __syncthreads();

    // ---------------- Phase 2: per-group attention ----------------
    const int ib = tid >> 3;    // rows i = ib*3 + ii
    const int jb = tid & 7;     // cols j = jb*12 + jj

    for (int g = 0; g < 8; ++g) {
        const int gb = g * 16;
        const float simA = sim_gamma[g] * rsqrtf(sim_var[g] + EPS);
        // sim_beta / sim_mean are j-independent -> cancel in softmax

        float q[4][3];
        #pragma unroll
        for (int c = 0; c < 4; ++c)
            #pragma unroll
            for (int ii = 0; ii < 3; ++ii)
                q[c][ii] = QKV[gb + c][ib * 3 + ii];

        float sim[3][12];
        #pragma unroll
        for (int ii = 0; ii < 3; ++ii)
            #pragma unroll
            for (int jj = 0; jj < 12; ++jj) sim[ii][jj] = 0.f;

        #pragma unroll
        for (int c = 0; c < 4; ++c) {
            float4 k0 = *reinterpret_cast<const float4*>(&QKV[gb + 4 + c][jb * 12]);
            float4 k1 = *reinterpret_cast<const float4*>(&QKV[gb + 4 + c][jb * 12 + 4]);
            float4 k2 = *reinterpret_cast<const float4*>(&QKV[gb + 4 + c][jb * 12 + 8]);
            float kk[12] = {k0.x, k0.y, k0.z, k0.w, k1.x, k1.y, k1.z, k1.w,
                            k2.x, k2.y, k2.z, k2.w};
            #pragma unroll
            for (int jj = 0; jj < 12; ++jj)
                #pragma unroll
                for (int ii = 0; ii < 3; ++ii)
                    sim[ii][jj] += q[c][ii] * kk[jj];
        }

        float p[3] = {0.f, 0.f, 0.f};
        #pragma unroll
        for (int ii = 0; ii < 3; ++ii)
            #pragma unroll
            for (int jj = 0; jj < 12; ++jj) {
                float e = __expf(simA * sim[ii][jj]);
                sim[ii][jj] = e;
                p[ii] += e;
            }
        #pragma unroll
        for (int ii = 0; ii < 3; ++ii) {
            p[ii] += __shfl_xor(p[ii], 1);
            p[ii] += __shfl_xor(p[ii], 2);
            p[ii] += __shfl_xor(p[ii], 4);
        }
        float zinv[3] = {1.f / p[0], 1.f / p[1], 1.f / p[2]};

        float sv[8][3];
        #pragma unroll
        for (int c = 0; c < 8; ++c)
            #pragma unroll
            for (int ii = 0; ii < 3; ++ii) sv[c][ii] = 0.f;

        #pragma unroll
        for (int c = 0; c < 8; ++c) {
            float4 v0 = *reinterpret_cast<const float4*>(&QKV[gb + 8 + c][jb * 12]);
            float4 v1 = *reinterpret_cast<const float4*>(&QKV[gb + 8 + c][jb * 12 + 4]);
            float4 v2 = *reinterpret_cast<const float4*>(&QKV[gb + 8 + c][jb * 12 + 8]);
            float vv[12] = {v0.x, v0.y, v0.z, v0.w, v1.x, v1.y, v1.z, v1.w,
                            v2.x, v2.y, v2.z, v2.w};
            #pragma unroll
            for (int jj = 0; jj < 12; ++jj)
                #pragma unroll
                for (int ii = 0; ii < 3; ++ii)
                    sv[c][ii] += sim[ii][jj] * vv[jj];
        }
        #pragma unroll
        for (int c = 0; c < 8; ++c)
            #pragma unroll
            for (int ii = 0; ii < 3; ++ii) {
                sv[c][ii] += __shfl_xor(sv[c][ii], 1);
                sv[c][ii] += __shfl_xor(sv[c][ii], 2);
                sv[c][ii] += __shfl_xor(sv[c][ii], 4);
            }

        // stage into QKV pad columns: flat idx = c*96 + i  ->  [idx>>3][96+(idx&7)]
        if (jb == 0) {
            #pragma unroll
            for (int c = 0; c < 8; ++c) {
                int d = g * 8 + c;
                float osc = out_gamma[d] * rsqrtf(out_var[d] + EPS);
                float ob  = out_beta[d] - out_mean[d] * osc;
                #pragma unroll
                for (int ii = 0; ii < 3; ++ii) {
                    int idx = c * 96 + ib * 3 + ii;
                    QKV[idx >> 3][96 + (idx & 7)] = sv[c][ii] * zinv[ii] * osc + ob;
                }
            }
        }
        __syncthreads();

        if (DIRECT) {
            #pragma unroll
            for (int t = 0; t < 3; ++t) {
                int idx = tid * 3 + t;
                int d = idx / 96, cl = idx - d * 96;
                dst[(size_t)nt * 393216 + (size_t)cl * 4096 + (size_t)(g * 8 + d) * 64 + hs]
                    = QKV[idx >> 3][96 + (idx & 7)];
            }
        } else {
            if (tid < 192) {
                float4 vv = *reinterpret_cast<const float4*>(&QKV[tid >> 1][96 + 4 * (tid & 1)]);
                reinterpret_cast<float4*>(dst)[(size_t)b * 1536 + g * 192 + tid] = vv;
            }
        }
        __syncthreads();   // pad reused next group
    }
}

// ws (nt, hs, d, cl) -> out (nt, cl, d, hs); block = (nt, d-pair):
// reads 768B-aligned segments, writes 512B-aligned segments (zero line amplification).
__global__ __launch_bounds__(256) void transpose_kernel(const float* __restrict__ ws,
                                                        float* __restrict__ out)
{
    __shared__ float tile[2][64][97];
    const int blk = blockIdx.x;          // nt*32 + dp
    const int nt = blk >> 5, dp = blk & 31;
    const float4* ws4 = reinterpret_cast<const float4*>(ws);
    float4* out4 = reinterpret_cast<float4*>(out);

    for (int idx = threadIdx.x; idx < 3072; idx += 256) {
        int hsr = idx / 48, rem = idx - hsr * 48;
        int dd = rem / 24, c4 = rem - dd * 24;
        float4 v = ws4[(size_t)nt * 98304 + (size_t)hsr * 1536 + (size_t)(dp * 2 + dd) * 24 + c4];
        tile[dd][hsr][c4 * 4 + 0] = v.x;
        tile[dd][hsr][c4 * 4 + 1] = v.y;
        tile[dd][hsr][c4 * 4 + 2] = v.z;
        tile[dd][hsr][c4 * 4 + 3] = v.w;
    }
    __syncthreads();

    for (int idx = threadIdx.x; idx < 3072; idx += 256) {
        int cl = idx >> 5, rem = idx & 31;
        int dd = rem >> 4, h4 = rem & 15;
        float4 v = make_float4(tile[dd][h4 * 4 + 0][cl], tile[dd][h4 * 4 + 1][cl],
                               tile[dd][h4 * 4 + 2][cl], tile[dd][h4 * 4 + 3][cl]);
        out4[(size_t)nt * 98304 + (size_t)cl * 1024 + (size_t)(dp * 2 + dd) * 16 + h4] = v;
    }
}

extern "C" void kernel_launch(void* const* d_in, const int* in_sizes, int n_in,
                              void* d_out, int out_size, void* d_ws, size_t ws_size,
                              hipStream_t stream) {
    const float* x         = (const float*)d_in[0];
    const float* w_qkv     = (const float*)d_in[1];
    const float* qkv_gamma = (const float*)d_in[2];
    const float* qkv_beta  = (const float*)d_in[3];
    const float* qkv_mean  = (const float*)d_in[4];
    const float* qkv_var   = (const float*)d_in[5];
    const float* sim_gamma = (const float*)d_in[6];
    const float* sim_beta  = (const float*)d_in[7];
    const float* sim_mean  = (const float*)d_in[8];
    const float* sim_var   = (const float*)d_in[9];
    const float* out_gamma = (const float*)d_in[10];
    const float* out_beta  = (const float*)d_in[11];
    const float* out_mean  = (const float*)d_in[12];
    const float* out_var   = (const float*)d_in[13];
    float* out = (float*)d_out;

    const size_t ws_need = (size_t)2048 * 6144 * sizeof(float);  // 50.3 MB

    if (ws_size >= ws_need) {
        float* wsb = (float*)d_ws;
        attn_kernel<false><<<2048, 256, 0, stream>>>(
            x, w_qkv, qkv_gamma, qkv_beta, qkv_mean, qkv_var,
            sim_gamma, sim_beta, sim_mean, sim_var,
            out_gamma, out_beta, out_mean, out_var, wsb);
        transpose_kernel<<<1024, 256, 0, stream>>>(wsb, out);
    } else {
        attn_kernel<true><<<2048, 256, 0, stream>>>(
            x, w_qkv, qkv_gamma, qkv_beta, qkv_mean, qkv_var,
            sim_gamma, sim_beta, sim_mean, sim_var,
            out_gamma, out_beta, out_mean, out_var, out);
    }
}

// Round 4
// 208.472 us; speedup vs baseline: 3.5311x; 1.4366x over previous
//
#include <hip/hip_runtime.h>

#define EPS 1e-5f

typedef short v8s __attribute__((ext_vector_type(8)));
typedef float v4f __attribute__((ext_vector_type(4)));

__device__ inline unsigned short f2bf(float f) {
    union { float f; unsigned u; } v; v.f = f;
    unsigned r = v.u + 0x7FFFu + ((v.u >> 16) & 1u);
    return (unsigned short)(r >> 16);
}
__device__ inline unsigned pack2(float a, float b) {
    return (unsigned)f2bf(a) | ((unsigned)f2bf(b) << 16);
}

// LDS map (52,480 B total -> 3 blocks/CU):
//   [0      .. 25600)  QKf  float[64][100]   Q(rows r<4, pre-scaled by simA) + K fp32
//   [25600  .. 38912)  Vb   ushort[64][104]  V bf16 (B-operand rows)
//   [38912  .. 48896)  Pb   ushort[48][104]  P strip bf16 (A-operand rows)
//   [48896  .. 49280)  zbuf float[96]        1/Z per row
//   [49280  .. 52480)  sbuf float[8][100]    per-group output staging
//   phase-1 overlay: Xb ushort[96][72] @0, Wb ushort[128][72] @13824 (dead before QKf written)
template<bool DIRECT>
__global__ __launch_bounds__(256, 3) void attn_kernel(
    const float* __restrict__ x,
    const float* __restrict__ w,
    const float* __restrict__ qkv_gamma, const float* __restrict__ qkv_beta,
    const float* __restrict__ qkv_mean,  const float* __restrict__ qkv_var,
    const float* __restrict__ sim_gamma, const float* __restrict__ sim_beta,
    const float* __restrict__ sim_mean,  const float* __restrict__ sim_var,
    const float* __restrict__ out_gamma, const float* __restrict__ out_beta,
    const float* __restrict__ out_mean,  const float* __restrict__ out_var,
    float* __restrict__ dst)
{
    __shared__ __align__(16) unsigned char smem[52480];
    float (*QKf)[100]         = (float(*)[100])smem;
    unsigned short (*Vb)[104] = (unsigned short(*)[104])(smem + 25600);
    unsigned short (*Pb)[104] = (unsigned short(*)[104])(smem + 38912);
    float* zbuf               = (float*)(smem + 48896);
    float (*sbuf)[100]        = (float(*)[100])(smem + 49280);
    unsigned short (*Xb)[72]  = (unsigned short(*)[72])smem;
    unsigned short (*Wb)[72]  = (unsigned short(*)[72])(smem + 13824);

    const int tid  = threadIdx.x;
    const int lane = tid & 63;
    const int wid  = tid >> 6;
    const int quad = lane >> 4;
    const int b  = blockIdx.x;          // b = nt*64 + hs
    const int nt = b >> 6;
    const int hs = b & 63;

    const float* xb = x + (size_t)nt * 393216 + (size_t)hs * 64;
    const float4* x4 = reinterpret_cast<const float4*>(xb);
    const float4* w4 = reinterpret_cast<const float4*>(w);

    // ---------------- Phase 1a: stage X, W as bf16 ----------------
    #pragma unroll
    for (int it = 0; it < 6; ++it) {
        int idx = tid + it * 256;               // 1536 float4s
        int cl = idx >> 4, v = idx & 15;
        float4 val = x4[cl * 1024 + v];
        unsigned* dx = (unsigned*)&Xb[cl][v * 4];
        dx[0] = pack2(val.x, val.y);
        dx[1] = pack2(val.z, val.w);
    }
    #pragma unroll
    for (int it = 0; it < 8; ++it) {
        int idx = tid + it * 256;               // 2048 float4s
        int r = idx >> 4, v = idx & 15;
        float4 val = w4[r * 16 + v];
        unsigned* dw = (unsigned*)&Wb[r][v * 4];
        dw[0] = pack2(val.x, val.y);
        dw[1] = pack2(val.z, val.w);
    }
    __syncthreads();

    // ---------------- Phase 1b: QKV = W @ X via MFMA ----------------
    // wave w owns m-tiles {2w, 2w+1} x all 6 n-tiles, K = 2 tiles of 32
    v4f acc[2][6];
    #pragma unroll
    for (int mi = 0; mi < 2; ++mi)
        #pragma unroll
        for (int ni = 0; ni < 6; ++ni) acc[mi][ni] = (v4f)(0.f);

    #pragma unroll
    for (int kt = 0; kt < 2; ++kt) {
        v8s a0 = *reinterpret_cast<const v8s*>(&Wb[(wid * 2 + 0) * 16 + (lane & 15)][kt * 32 + quad * 8]);
        v8s a1 = *reinterpret_cast<const v8s*>(&Wb[(wid * 2 + 1) * 16 + (lane & 15)][kt * 32 + quad * 8]);
        #pragma unroll
        for (int ni = 0; ni < 6; ++ni) {
            v8s bfr = *reinterpret_cast<const v8s*>(&Xb[ni * 16 + (lane & 15)][kt * 32 + quad * 8]);
            acc[0][ni] = __builtin_amdgcn_mfma_f32_16x16x32_bf16(a0, bfr, acc[0][ni], 0, 0, 0);
            acc[1][ni] = __builtin_amdgcn_mfma_f32_16x16x32_bf16(a1, bfr, acc[1][ni], 0, 0, 0);
        }
    }
    __syncthreads();    // staging dead; region becomes QKf

    // epilogue: BN; rows r<8 of each 16 -> QKf fp32 (Q rows scaled by simA); r>=8 -> Vb bf16
    #pragma unroll
    for (int mi = 0; mi < 2; ++mi) {
        const int mt = wid * 2 + mi;            // = group g
        #pragma unroll
        for (int reg = 0; reg < 4; ++reg) {
            int o = mt * 16 + quad * 4 + reg;
            int r = o & 15;
            float sc = qkv_gamma[o] * rsqrtf(qkv_var[o] + EPS);
            float mb = qkv_beta[o] - qkv_mean[o] * sc;
            float sA = sim_gamma[mt] * rsqrtf(sim_var[mt] + EPS);
            if (r < 4) { sc *= sA; mb *= sA; }
            if (r < 8) {
                #pragma unroll
                for (int ni = 0; ni < 6; ++ni)
                    QKf[mt * 8 + r][ni * 16 + (lane & 15)] = acc[mi][ni][reg] * sc + mb;
            } else {
                #pragma unroll
                for (int ni = 0; ni < 6; ++ni)
                    Vb[mt * 8 + (r - 8)][ni * 16 + (lane & 15)] = f2bf(acc[mi][ni][reg] * sc + mb);
            }
        }
    }
    __syncthreads();

    // ---------------- Phase 2: per-group attention ----------------
    const int ib = tid >> 3;    // 0..31 : rows i = ib*3 + ii
    const int jb = tid & 7;     // 0..7  : cols j = jb*12 + jj

    for (int g = 0; g < 8; ++g) {
        // ---- scores (fp32 VALU, K=4; Q pre-scaled by simA; additive BN terms cancel) ----
        float q[4][3];
        #pragma unroll
        for (int c = 0; c < 4; ++c)
            #pragma unroll
            for (int ii = 0; ii < 3; ++ii)
                q[c][ii] = QKf[g * 8 + c][ib * 3 + ii];

        float sim[3][12];
        #pragma unroll
        for (int ii = 0; ii < 3; ++ii)
            #pragma unroll
            for (int jj = 0; jj < 12; ++jj) sim[ii][jj] = 0.f;

        #pragma unroll
        for (int c = 0; c < 4; ++c) {
            const float* kr = &QKf[g * 8 + 4 + c][jb * 12];
            v4f kA = *reinterpret_cast<const v4f*>(kr);
            v4f kB = *reinterpret_cast<const v4f*>(kr + 4);
            v4f kC = *reinterpret_cast<const v4f*>(kr + 8);
            #pragma unroll
            for (int ii = 0; ii < 3; ++ii) {
                float qq = q[c][ii];
                sim[ii][0] += qq * kA.x; sim[ii][1]  += qq * kA.y;
                sim[ii][2] += qq * kA.z; sim[ii][3]  += qq * kA.w;
                sim[ii][4] += qq * kB.x; sim[ii][5]  += qq * kB.y;
                sim[ii][6] += qq * kB.z; sim[ii][7]  += qq * kB.w;
                sim[ii][8] += qq * kC.x; sim[ii][9]  += qq * kC.y;
                sim[ii][10] += qq * kC.z; sim[ii][11] += qq * kC.w;
            }
        }

        float p[3] = {0.f, 0.f, 0.f};
        #pragma unroll
        for (int ii = 0; ii < 3; ++ii)
            #pragma unroll
            for (int jj = 0; jj < 12; ++jj) {
                float e = __expf(sim[ii][jj]);
                sim[ii][jj] = e;
                p[ii] += e;
            }
        #pragma unroll
        for (int ii = 0; ii < 3; ++ii) {
            p[ii] += __shfl_xor(p[ii], 1);
            p[ii] += __shfl_xor(p[ii], 2);
            p[ii] += __shfl_xor(p[ii], 4);
        }
        if (jb == 0) {
            #pragma unroll
            for (int ii = 0; ii < 3; ++ii)
                zbuf[ib * 3 + ii] = __builtin_amdgcn_rcpf(p[ii]);
        }

        // ---- two i-strips: P -> LDS (bf16, unnormalized), PV via MFMA ----
        #pragma unroll
        for (int s = 0; s < 2; ++s) {
            if ((tid >> 7) == s) {              // waves owning rows of this strip
                int rb = (ib - s * 16) * 3;
                #pragma unroll
                for (int ii = 0; ii < 3; ++ii) {
                    uint2* pr = (uint2*)&Pb[rb + ii][jb * 12];
                    uint2 v0, v1;
                    v0.x = pack2(sim[ii][0], sim[ii][1]);
                    v0.y = pack2(sim[ii][2], sim[ii][3]);
                    v1.x = pack2(sim[ii][4], sim[ii][5]);
                    v1.y = pack2(sim[ii][6], sim[ii][7]);
                    pr[0] = v0;
                    pr[1] = v1;
                    ((unsigned*)pr)[4] = pack2(sim[ii][8], sim[ii][9]);
                    ((unsigned*)pr)[5] = pack2(sim[ii][10], sim[ii][11]);
                }
            }
            __syncthreads();

            if (wid < 3) {                      // wave = m-tile of the 48-row strip
                const int mt = wid;
                v4f pv = (v4f)(0.f);
                #pragma unroll
                for (int kt = 0; kt < 3; ++kt) {
                    v8s a = *reinterpret_cast<const v8s*>(&Pb[mt * 16 + (lane & 15)][kt * 32 + quad * 8]);
                    v8s bv = *reinterpret_cast<const v8s*>(&Vb[g * 8 + (lane & 7)][kt * 32 + quad * 8]);
                    pv = __builtin_amdgcn_mfma_f32_16x16x32_bf16(a, bv, pv, 0, 0, 0);
                }
                if ((lane & 15) < 8) {
                    int c = lane & 15;
                    int d = g * 8 + c;
                    float osc = out_gamma[d] * rsqrtf(out_var[d] + EPS);
                    float ob  = out_beta[d] - out_mean[d] * osc;
                    v4f z = *reinterpret_cast<const v4f*>(&zbuf[s * 48 + mt * 16 + quad * 4]);
                    float4 o4;
                    o4.x = pv[0] * (z[0] * osc) + ob;
                    o4.y = pv[1] * (z[1] * osc) + ob;
                    o4.z = pv[2] * (z[2] * osc) + ob;
                    o4.w = pv[3] * (z[3] * osc) + ob;
                    *reinterpret_cast<float4*>(&sbuf[c][s * 48 + mt * 16 + quad * 4]) = o4;
                }
            }
            __syncthreads();
        }

        // ---- store this group's 8x96 block ----
        if (DIRECT) {
            #pragma unroll
            for (int t = 0; t < 3; ++t) {
                int idx = tid * 3 + t;
                int dd = idx / 96, cl = idx - dd * 96;
                dst[(size_t)nt * 393216 + (size_t)cl * 4096 + (size_t)(g * 8 + dd) * 64 + hs]
                    = sbuf[dd][cl];
            }
        } else {
            if (tid < 192) {
                int c = tid / 24, r = tid - c * 24;
                float4 vv = *reinterpret_cast<const float4*>(&sbuf[c][r * 4]);
                reinterpret_cast<float4*>(dst)[(size_t)b * 1536 + g * 192 + tid] = vv;
            }
        }
        __syncthreads();   // sbuf/zbuf reused next group
    }
}

// ws (nt, hs, d, cl) -> out (nt, cl, d, hs); block = (nt, d-pair)
__global__ __launch_bounds__(256) void transpose_kernel(const float* __restrict__ ws,
                                                        float* __restrict__ out)
{
    __shared__ float tile[2][64][97];
    const int blk = blockIdx.x;          // nt*32 + dp
    const int nt = blk >> 5, dp = blk & 31;
    const float4* ws4 = reinterpret_cast<const float4*>(ws);
    float4* out4 = reinterpret_cast<float4*>(out);

    for (int idx = threadIdx.x; idx < 3072; idx += 256) {
        int hsr = idx / 48, rem = idx - hsr * 48;
        int dd = rem / 24, c4 = rem - dd * 24;
        float4 v = ws4[(size_t)nt * 98304 + (size_t)hsr * 1536 + (size_t)(dp * 2 + dd) * 24 + c4];
        tile[dd][hsr][c4 * 4 + 0] = v.x;
        tile[dd][hsr][c4 * 4 + 1] = v.y;
        tile[dd][hsr][c4 * 4 + 2] = v.z;
        tile[dd][hsr][c4 * 4 + 3] = v.w;
    }
    __syncthreads();

    for (int idx = threadIdx.x; idx < 3072; idx += 256) {
        int cl = idx >> 5, rem = idx & 31;
        int dd = rem >> 4, h4 = rem & 15;
        float4 v = make_float4(tile[dd][h4 * 4 + 0][cl], tile[dd][h4 * 4 + 1][cl],
                               tile[dd][h4 * 4 + 2][cl], tile[dd][h4 * 4 + 3][cl]);
        out4[(size_t)nt * 98304 + (size_t)cl * 1024 + (size_t)(dp * 2 + dd) * 16 + h4] = v;
    }
}

extern "C" void kernel_launch(void* const* d_in, const int* in_sizes, int n_in,
                              void* d_out, int out_size, void* d_ws, size_t ws_size,
                              hipStream_t stream) {
    const float* x         = (const float*)d_in[0];
    const float* w_qkv     = (const float*)d_in[1];
    const float* qkv_gamma = (const float*)d_in[2];
    const float* qkv_beta  = (const float*)d_in[3];
    const float* qkv_mean  = (const float*)d_in[4];
    const float* qkv_var   = (const float*)d_in[5];
    const float* sim_gamma = (const float*)d_in[6];
    const float* sim_beta  = (const float*)d_in[7];
    const float* sim_mean  = (const float*)d_in[8];
    const float* sim_var   = (const float*)d_in[9];
    const float* out_gamma = (const float*)d_in[10];
    const float* out_beta  = (const float*)d_in[11];
    const float* out_mean  = (const float*)d_in[12];
    const float* out_var   = (const float*)d_in[13];
    float* out = (float*)d_out;

    const size_t ws_need = (size_t)2048 * 6144 * sizeof(float);  // 50.3 MB

    if (ws_size >= ws_need) {
        float* wsb = (float*)d_ws;
        attn_kernel<false><<<2048, 256, 0, stream>>>(
            x, w_qkv, qkv_gamma, qkv_beta, qkv_mean, qkv_var,
            sim_gamma, sim_beta, sim_mean, sim_var,
            out_gamma, out_beta, out_mean, out_var, wsb);
        transpose_kernel<<<1024, 256, 0, stream>>>(wsb, out);
    } else {
        attn_kernel<true><<<2048, 256, 0, stream>>>(
            x, w_qkv, qkv_gamma, qkv_beta, qkv_mean, qkv_var,
            sim_gamma, sim_beta, sim_mean, sim_var,
            out_gamma, out_beta, out_mean, out_var, out);
    }
}